// Round 5
// baseline (124.778 us; speedup 1.0000x reference)
//
#include <hip/hip_runtime.h>

// binary_decoder: bit-exact float32 emulation of the reference's sequential
// carry-save adder (absmax == 0.0 verified rounds 1-4).
//
// Round-5 changes (diagnosis: 61 cyc/step in round 4 with memory absolved ->
// recurrence-latency bound; the v_cmp->vcc->v_cndmask round-trips sat on the
// critical cycle and inflated issue to ~17 instr/step):
//  - vcc-free chain using the reference's own formulation:
//      hm = t * 0.5 ; h = floor(hm)            (plain VALU, no vcc)
//      s  = fma(-2, h, t)                      (== t - 2*half, single rounding)
//      c_raw = dpp_row_shr1(h)                 (unmasked)
//      t' = fma(c_raw, lsbmask, uu)            (== uu + c: c_raw*lsbmask exact)
//    lsbmask = 0 on lanes (lane&7)==0 receivers of a foreign h (lanes 8,24,..);
//    lanes 0,16,32,48 are bound_ctrl-zeroed by DPP. Critical cycle = 5 plain
//    VALU ops (~20-24 cyc) vs ~61 before.
//  - pack kernel vectorized: float4 loads / uint4 stores, 1024 waves
//    (was 64-thread scalar-load blocks, ~20 us -> ~6 us memory-bound).
//
// Exactness: a = bits&x == x*hard (x>=0); uu = fp32(s+a); t = fp32(uu+c) with
// c = c_raw*lsbmask in {0,1} exact, fma rounds once == v_add; t in [0,4) so
// h = floor(t/2) in {0,1}; s = t-2h exact on [2,4). Matches the np reference
// op-for-op in fp32.

#define F_DIM 2048
#define K_DIM 4096
#define B_DIM 8
#define G     32            // steps per group = bits per packed dword
#define NG    (F_DIM / G)   // 64 groups
#define NB2   4             // rotating buffer depth (prefetch distance 3 groups)

#define PK_BYTES (64 * NG * 64 * 4)  // 1 MB: [og][f32][lane] dwords

__device__ __forceinline__ float dpp_row_shr1(float v) {
    // row_shr:1 (0x111), all rows/banks, bound_ctrl: out-of-row source -> 0
    int r = __builtin_amdgcn_update_dpp(0, __float_as_int(v), 0x111, 0xf, 0xf, true);
    return __int_as_float(r);
}

__device__ __forceinline__ int sext_bit(unsigned bits, int u) {
#if __has_builtin(__builtin_amdgcn_sbfe)
    return __builtin_amdgcn_sbfe((int)bits, (unsigned)u, 1u);  // v_bfe_i32
#else
    return ((int)(bits << (31 - u))) >> 31;
#endif
}

// ---------------- pass 1: pack (w >= 0.5) bits -----------------------------
// pk[(og*64 + f32)*64 + col] bit j = (w[(f32*32+j)][og*64+col] >= 0.5)
// Block = 64 threads; thread t handles 4 consecutive columns 4t..4t+3 of a
// 256-column slab (ogq = 4 og's). float4 loads (lane-contiguous 1 KB/row),
// uint4 stores (contiguous within each og's 64-dword row).
__global__ __launch_bounds__(64) void pack_kernel(const float* __restrict__ w,
                                                  unsigned* __restrict__ pk) {
    const int t   = threadIdx.x;       // 0..63
    const int ogq = blockIdx.x;        // 0..15  (4 og's per block)
    const int f32 = blockIdx.y;        // 0..63

    const float4* w4 = (const float4*)(w + ogq * 256) + t; // +K_DIM/4 per row

    unsigned b0 = 0, b1 = 0, b2 = 0, b3 = 0;
#pragma unroll
    for (int j = 0; j < 32; ++j) {
        float4 v = w4[(f32 * 32 + j) * (K_DIM / 4)];
        b0 |= (v.x >= 0.5f ? 1u : 0u) << j;
        b1 |= (v.y >= 0.5f ? 1u : 0u) << j;
        b2 |= (v.z >= 0.5f ? 1u : 0u) << j;
        b3 |= (v.w >= 0.5f ? 1u : 0u) << j;
    }
    const int og  = ogq * 4 + (t >> 4);       // 4t..4t+3 stay inside one og
    const int col = (t & 15) * 4;
    uint4* dst = (uint4*)(pk + (og * NG + f32) * 64 + col);
    *dst = make_uint4(b0, b1, b2, b3);
}

// ---------------- pass 2: the sequential chain -----------------------------
__global__ __launch_bounds__(64, 1) void csa_main(const float* __restrict__ x,
                                                  const unsigned* __restrict__ pk,
                                                  float* __restrict__ out) {
    const int lane = threadIdx.x;                 // 0..63
    const int og   = blockIdx.x + 8 * blockIdx.y; // 0..63
    const int b    = blockIdx.z;                  // 0..7
    const int k    = og * 64 + lane;

    // carry-in mask on the RECEIVING side: LSB bit-lane of each chain gets 0.
    const float lsbmask = ((lane & 7) == 0) ? 0.0f : 1.0f;

    // Opaque zero: keep the x address out of the SMEM (lgkmcnt) domain.
    int zero;
    asm volatile("v_mov_b32 %0, 0" : "=v"(zero));

    const unsigned* bp  = pk + og * (NG * 64) + lane;           // +64 per group
    const float4*   xp4 = (const float4*)(x + b * F_DIM) + zero;

    unsigned bbuf[NB2];
    float4   xb[NB2][G / 4];

    // prologue: groups 0..NB2-1
#pragma unroll
    for (int p = 0; p < NB2; ++p) {
        bbuf[p] = bp[p * 64];
#pragma unroll
        for (int q = 0; q < G / 4; ++q)
            xb[p][q] = xp4[p * (G / 4) + q];
    }

    float s = 0.0f, craw = 0.0f;

    for (int g0 = 0; g0 < NG; g0 += NB2) {   // 16 iterations
#pragma unroll
        for (int p = 0; p < NB2; ++p) {
            const float*   xf   = (const float*)&xb[p][0];
            const unsigned bits = bbuf[p];
#pragma unroll
            for (int u = 0; u < G; ++u) {
                int   m  = sext_bit(bits, u);                         // off-chain
                float a  = __int_as_float(m & __float_as_int(xf[u])); // == x*hard
                float uu = s + a;                   // fp32(s + a)
                float t  = fmaf(craw, lsbmask, uu); // fp32(uu + c), exact c
                float h  = floorf(t * 0.5f);        // in {0,1}, no vcc
                s = fmaf(-2.0f, h, t);              // == t - 2*half
                craw = dpp_row_shr1(h);             // carry toward MSB lane
            }
            // refill for use NB2-1 groups later (clamped tail re-read)
            int gb = g0 + p + NB2;
            int gc = (gb < NG) ? gb : (NG - 1);
            bbuf[p] = bp[gc * 64];
#pragma unroll
            for (int q = 0; q < G / 4; ++q)
                xb[p][q] = xp4[gc * (G / 4) + q];
        }
    }

    out[b * K_DIM + k]                 = s;
    out[B_DIM * K_DIM + b * K_DIM + k] = craw * lsbmask;  // final masked carry
}

// ---------------- fallback (round-3 kernel) if ws is too small -------------
#define U_FB  16
#define NB_FB 4
__global__ __launch_bounds__(64, 1) void csa_fallback(const float* __restrict__ x,
                                                      const float* __restrict__ weight,
                                                      float* __restrict__ out) {
    const int lane = threadIdx.x;
    const int og   = blockIdx.x + 8 * blockIdx.y;
    const int b    = blockIdx.z;
    const int k    = og * 64 + lane;
    const float lsbmask = ((lane & 7) == 0) ? 0.0f : 1.0f;
    int zero;
    asm volatile("v_mov_b32 %0, 0" : "=v"(zero));
    const float*  wp  = weight + k;
    const float4* xp4 = (const float4*)(x + b * F_DIM) + zero;
    float  wb[NB_FB][U_FB];
    float4 xb[NB_FB][U_FB / 4];
#pragma unroll
    for (int p = 0; p < NB_FB; ++p) {
#pragma unroll
        for (int u = 0; u < U_FB; ++u) wb[p][u] = wp[(p * U_FB + u) * K_DIM];
#pragma unroll
        for (int q = 0; q < U_FB / 4; ++q) xb[p][q] = xp4[(p * U_FB) / 4 + q];
    }
    float s = 0.0f, craw = 0.0f;
    for (int f0 = 0; f0 < F_DIM; f0 += NB_FB * U_FB) {
#pragma unroll
        for (int p = 0; p < NB_FB; ++p) {
            const float* xf = (const float*)&xb[p][0];
#pragma unroll
            for (int u = 0; u < U_FB; ++u) {
                float a  = (wb[p][u] >= 0.5f) ? xf[u] : 0.0f;
                float uu = s + a;
                float t  = fmaf(craw, lsbmask, uu);
                float h  = floorf(t * 0.5f);
                s = fmaf(-2.0f, h, t);
                craw = dpp_row_shr1(h);
            }
            int fb = f0 + p * U_FB + NB_FB * U_FB;
            int fc = (fb <= F_DIM - U_FB) ? fb : (F_DIM - U_FB);
#pragma unroll
            for (int u = 0; u < U_FB; ++u) wb[p][u] = wp[(fc + u) * K_DIM];
#pragma unroll
            for (int q = 0; q < U_FB / 4; ++q) xb[p][q] = xp4[fc / 4 + q];
        }
    }
    out[b * K_DIM + k]                 = s;
    out[B_DIM * K_DIM + b * K_DIM + k] = craw * lsbmask;
}

extern "C" void kernel_launch(void* const* d_in, const int* in_sizes, int n_in,
                              void* d_out, int out_size, void* d_ws, size_t ws_size,
                              hipStream_t stream) {
    (void)in_sizes; (void)n_in; (void)out_size;
    const float* x      = (const float*)d_in[0];
    const float* weight = (const float*)d_in[1];
    float* out          = (float*)d_out;

    if (ws_size >= (size_t)PK_BYTES && d_ws != nullptr) {
        unsigned* pk = (unsigned*)d_ws;
        pack_kernel<<<dim3(16, 64, 1), dim3(64), 0, stream>>>(weight, pk);
        csa_main<<<dim3(8, 8, 8), dim3(64), 0, stream>>>(x, pk, out);
    } else {
        csa_fallback<<<dim3(8, 8, 8), dim3(64), 0, stream>>>(x, weight, out);
    }
}